// Round 7
// baseline (91.094 us; speedup 1.0000x reference)
//
#include <hip/hip_runtime.h>
#include <math.h>

#define HIDDEN 1024
#define NL 9
#define LEAN_TAU 0.25f
#define LEAN_DELTA 0.35f
#define LCH 16  // CRF scan chunk length
#define TPW 4   // tokens per wave in logits_k

// ---------------- Kernel 1: emission logits + lean adjust ----------------
// Wave-per-4-tokens, lanes split H (coalesced 1KB loads). ALL 16 row-loads
// are issued into dedicated registers BEFORE any FMA consumes them -> ~16KB
// outstanding per wave (fixes the VGPR-starved serial-load latency bound
// diagnosed in R5/R6: VGPR_Count=56 => ~1 load in flight => 1-2 TB/s).
__global__ __launch_bounds__(256) void logits_k(
    const float* __restrict__ hs, const float* __restrict__ w,
    const float* __restrict__ bias, const int* __restrict__ amask,
    float* __restrict__ e, int B, int T) {
  __shared__ float lw[NL * HIDDEN];
  const int TOK = T - 2;
  const int nTok = B * TOK;
  for (int i = threadIdx.x; i < NL * HIDDEN / 4; i += blockDim.x)
    reinterpret_cast<float4*>(lw)[i] = reinterpret_cast<const float4*>(w)[i];
  __syncthreads();
  const int wave = threadIdx.x >> 6, lane = threadIdx.x & 63;
  float bb9[NL];
#pragma unroll
  for (int l = 0; l < NL; ++l) bb9[l] = bias[l];

  for (int base = (blockIdx.x * 4 + wave) * TPW; base < nTok;
       base += gridDim.x * 4 * TPW) {
    bool act[TPW];
    int bs[TPW], ts[TPW];
    float4 hv[TPW][4];  // 64 VGPRs of in-flight load data
#pragma unroll
    for (int tk = 0; tk < TPW; ++tk) {
      const int tok = base + tk;
      act[tk] = tok < nTok;
      const int tokc = act[tk] ? tok : base;  // base always valid
      bs[tk] = tokc / TOK;
      ts[tk] = tokc - bs[tk] * TOK;
    }
    // ---- issue ALL 16 loads first (no consumption in between) ----
#pragma unroll
    for (int tk = 0; tk < TPW; ++tk) {
      const float4* row = reinterpret_cast<const float4*>(
          hs + ((size_t)bs[tk] * T + ts[tk] + 1) * HIDDEN);
#pragma unroll
      for (int k = 0; k < 4; ++k) hv[tk][k] = row[lane + 64 * k];
    }
    // ---- consume ----
    float acc[TPW][NL];
#pragma unroll
    for (int tk = 0; tk < TPW; ++tk)
#pragma unroll
      for (int l = 0; l < NL; ++l) acc[tk][l] = 0.f;
#pragma unroll
    for (int k = 0; k < 4; ++k) {
      const int h4 = lane + 64 * k;
#pragma unroll
      for (int l = 0; l < NL; ++l) {
        const float4 wv = reinterpret_cast<const float4*>(lw + l * HIDDEN)[h4];
#pragma unroll
        for (int tk = 0; tk < TPW; ++tk)
          acc[tk][l] = fmaf(hv[tk][k].x, wv.x,
                       fmaf(hv[tk][k].y, wv.y,
                       fmaf(hv[tk][k].z, wv.z,
                            fmaf(hv[tk][k].w, wv.w, acc[tk][l]))));
      }
    }

#pragma unroll
    for (int tk = 0; tk < TPW; ++tk) {
#pragma unroll
      for (int l = 0; l < NL; ++l) {
        float v = acc[tk][l];
#pragma unroll
        for (int off = 32; off; off >>= 1) v += __shfl_xor(v, off);
        acc[tk][l] = v + bb9[l];
      }
      float m1 = -INFINITY, m2 = -INFINITY;
#pragma unroll
      for (int l = 0; l < NL; ++l) {
        const float v = acc[tk][l];
        if (v > m1) { m2 = m1; m1 = v; }
        else if (v > m2) { m2 = v; }
      }
      const bool unc = (m1 - m2 < LEAN_TAU) &&
                       (amask[bs[tk] * T + ts[tk] + 1] != 0);
      if (unc) acc[tk][0] += LEAN_DELTA;
      if (act[tk] && lane < NL) {
        float outv = acc[tk][0];
#pragma unroll
        for (int l = 1; l < NL; ++l)
          if (lane == l) outv = acc[tk][l];
        e[(size_t)(base + tk) * NL + lane] = outv;
      }
    }
  }
}

// ---------------- Kernel 2: per-chunk log-space matrix products ----------------
// 7 chunks per wave; lane = sub*9 + i holds row i of chunk sub's 9x9 product.
// Factored logsumexp: W = exp(trans) in registers -> 9 exp + 9 log + 81 fma/step.
__global__ __launch_bounds__(64) void chunk_k(
    const float* __restrict__ e, const int* __restrict__ labels,
    const float* __restrict__ trans, float* __restrict__ Pout,
    int B, int T, int C) {
  const int TOK = T - 2;
  __shared__ float e2[7][LCH][NL];
  __shared__ float tr2[NL * NL];
  __shared__ int msk[7][LCH];
  const int tid = threadIdx.x;
  const int nG = B * C;
  const int gbase = blockIdx.x * 7;

  for (int idx = tid; idx < NL * NL; idx += 64) tr2[idx] = trans[idx];
  for (int idx = tid; idx < 7 * LCH * NL; idx += 64) {
    const int sub = idx / (LCH * NL), rem = idx % (LCH * NL);
    const int step = rem / NL, j = rem % NL;
    const int g = gbase + sub;
    if (g < nG) {
      const int b = g / C, c = g % C;
      const int t = 1 + c * LCH + step;
      if (t < TOK) e2[sub][step][j] = e[((size_t)b * TOK + t) * NL + j];
    }
  }
  for (int idx = tid; idx < 7 * LCH; idx += 64) {
    const int sub = idx / LCH, step = idx % LCH;
    const int g = gbase + sub;
    if (g < nG) {
      const int b = g / C, c = g % C;
      const int t = 1 + c * LCH + step;
      msk[sub][step] = (t < TOK) ? (labels[(size_t)b * T + 1 + t] != -100) : 0;
    }
  }
  __syncthreads();

  const int sub = tid / NL, i = tid % NL;  // sub==7 only for tid 63 (inactive)
  const int g = gbase + sub;
  const bool act = (sub < 7) && (g < nG);
  int len = 1;
  if (act) { const int c = g % C; len = min(LCH, TOK - (1 + c * LCH)); }

  float W[NL][NL];
#pragma unroll
  for (int k = 0; k < NL; ++k)
#pragma unroll
    for (int j = 0; j < NL; ++j) W[k][j] = __expf(tr2[k * NL + j]);

  float P[NL];
  {
    const int m0 = act ? msk[sub][0] : 0;
#pragma unroll
    for (int j = 0; j < NL; ++j)
      P[j] = m0 ? (tr2[i * NL + j] + e2[sub][0][j])
                : ((i == j) ? 0.f : -1e30f);
  }
  for (int step = 1; step < len; ++step) {
    const int mt = msk[sub][step];
    float mx = P[0];
#pragma unroll
    for (int k = 1; k < NL; ++k) mx = fmaxf(mx, P[k]);
    float E[NL];
#pragma unroll
    for (int k = 0; k < NL; ++k) E[k] = __expf(P[k] - mx);
    float Pn[NL];
#pragma unroll
    for (int j = 0; j < NL; ++j) {
      float s = 0.f;
#pragma unroll
      for (int k = 0; k < NL; ++k) s = fmaf(E[k], W[k][j], s);
      Pn[j] = mx + __logf(s) + e2[sub][step][j];
    }
#pragma unroll
    for (int j = 0; j < NL; ++j) P[j] = mt ? Pn[j] : P[j];
  }
  if (act) {
    float* dst = Pout + (size_t)g * 81 + i * NL;
#pragma unroll
    for (int j = 0; j < NL; ++j) dst[j] = P[j];
  }
}

// ---------------- Kernel 3: per-batch combine (num + den fold) ----------------
__global__ __launch_bounds__(64) void combine_k(
    const float* __restrict__ e, const int* __restrict__ labels,
    const float* __restrict__ start_t, const float* __restrict__ end_t,
    const float* __restrict__ trans, const float* __restrict__ Pmat,
    float* __restrict__ llh, int B, int T, int C) {
  const int TOK = T - 2;
  const int b = blockIdx.x, lane = threadIdx.x;
  const float* eb = e + (size_t)b * TOK * NL;
  const int* lb = labels + (size_t)b * T + 1;

  // ---- numerator: chain-free, data-parallel over t ----
  const int g0r = lb[0];
  const int tg0 = (g0r == -100) ? 0 : g0r;
  float nsum = 0.f;
  int pack = -1;  // (t<<4)|tag of last masked step
  for (int t = 1 + lane; t < TOK; t += 64) {
    const int gr = lb[t], pr = lb[t - 1];
    if (gr != -100) {
      const int cur = gr;
      const int prev = (pr == -100) ? 0 : pr;
      nsum += trans[prev * NL + cur] + eb[t * NL + cur];
      pack = (t << 4) | cur;
    }
  }
#pragma unroll
  for (int off = 32; off; off >>= 1) {
    nsum += __shfl_xor(nsum, off);
    pack = max(pack, __shfl_xor(pack, off));
  }
  const int last = (pack < 0) ? tg0 : (pack & 15);
  const float num = start_t[tg0] + eb[tg0] + nsum + end_t[last];

  // ---- denominator: fold C chunk matrices ----
  float alpha = (lane < NL) ? (start_t[lane] + eb[lane]) : -1e30f;
  for (int c = 0; c < C; ++c) {
    const float* Pc = Pmat + ((size_t)b * C + c) * 81;
    float col[NL];
#pragma unroll
    for (int i = 0; i < NL; ++i)
      col[i] = (lane < NL) ? Pc[i * NL + lane] : -1e30f;
    float s[NL];
    float mx = -1e30f;
#pragma unroll
    for (int i = 0; i < NL; ++i) {
      const float ai = __shfl(alpha, i);
      s[i] = ai + col[i];
      mx = fmaxf(mx, s[i]);
    }
    float sum = 0.f;
#pragma unroll
    for (int i = 0; i < NL; ++i) sum += __expf(s[i] - mx);
    const float nx = mx + __logf(sum);
    alpha = (lane < NL) ? nx : -1e30f;
  }
  const float v = (lane < NL) ? (alpha + end_t[lane]) : -1e30f;
  float mx = v;
#pragma unroll
  for (int off = 32; off; off >>= 1) mx = fmaxf(mx, __shfl_xor(mx, off));
  float sum = (lane < NL) ? __expf(v - mx) : 0.f;
#pragma unroll
  for (int off = 32; off; off >>= 1) sum += __shfl_xor(sum, off);
  const float den = mx + __logf(sum);
  if (lane == 0) llh[b] = num - den;
}

// ---------------- Kernel 4: -mean(llh) ----------------
__global__ __launch_bounds__(64) void reduce_k(const float* __restrict__ llh,
                                               float* __restrict__ out, int B) {
  float v = 0.f;
  for (int i = threadIdx.x; i < B; i += 64) v += llh[i];
#pragma unroll
  for (int off = 32; off; off >>= 1) v += __shfl_xor(v, off);
  if (threadIdx.x == 0) out[0] = -v / (float)B;
}

extern "C" void kernel_launch(void* const* d_in, const int* in_sizes, int n_in,
                              void* d_out, int out_size, void* d_ws,
                              size_t ws_size, hipStream_t stream) {
  const float* hs     = (const float*)d_in[0];
  const float* w      = (const float*)d_in[1];
  const float* bias   = (const float*)d_in[2];
  const float* st     = (const float*)d_in[3];
  const float* et     = (const float*)d_in[4];
  const float* tr     = (const float*)d_in[5];
  const int*   amask  = (const int*)d_in[6];
  const int*   labels = (const int*)d_in[7];

  const int T = 512;
  const int B = in_sizes[6] / T;
  const int TOK = T - 2;
  const int C = (TOK - 1 + LCH - 1) / LCH;  // chunks of the 509 recurrence steps

  float* e    = (float*)d_ws;                 // (B, TOK, 9)
  float* llh  = e + (size_t)B * TOK * NL;     // (B,)
  float* Pmat = llh + B;                      // (B*C, 81)

  const int nTok = B * TOK;
  const int tokPerBlk = 4 * TPW;              // 4 waves x TPW tokens
  logits_k<<<(nTok + tokPerBlk - 1) / tokPerBlk, 256, 0, stream>>>(
      hs, w, bias, amask, e, B, T);
  const int nG = B * C;
  chunk_k<<<(nG + 6) / 7, 64, 0, stream>>>(e, labels, tr, Pmat, B, T, C);
  combine_k<<<B, 64, 0, stream>>>(e, labels, st, et, tr, Pmat, llh, B, T, C);
  reduce_k<<<1, 64, 0, stream>>>(llh, (float*)d_out, B);
}

// Round 8
// 88.756 us; speedup vs baseline: 1.0263x; 1.0263x over previous
//
#include <hip/hip_runtime.h>
#include <math.h>

#define HIDDEN 1024
#define NL 9
#define LEAN_TAU 0.25f
#define LEAN_DELTA 0.35f
#define LCH 16  // CRF scan chunk length

// ---------------- Kernel 1: emission logits + lean adjust ----------------
// EXACT R2/R4 structure (measured ~30us): one wave per token, 4 waves/block,
// emis_w staged in LDS, grid-stride loop (cap 2048 blocks -> 4 iters/wave).
// R6/R7's TPW=4 register-batched variant regressed to ~72us (VGPR pressure);
// keep VGPR ~56 so 16 waves/CU hide latency.
__global__ __launch_bounds__(256) void logits_k(
    const float* __restrict__ hs, const float* __restrict__ w,
    const float* __restrict__ bias, const int* __restrict__ amask,
    float* __restrict__ e, int B, int T) {
  __shared__ float lw[NL * HIDDEN];
  const int TOK = T - 2;
  for (int i = threadIdx.x; i < NL * HIDDEN / 4; i += blockDim.x)
    reinterpret_cast<float4*>(lw)[i] = reinterpret_cast<const float4*>(w)[i];
  __syncthreads();
  const int wave = threadIdx.x >> 6, lane = threadIdx.x & 63;
  const int nTok = B * TOK;
  float bb9[NL];
#pragma unroll
  for (int l = 0; l < NL; ++l) bb9[l] = bias[l];
  for (int tok = blockIdx.x * 4 + wave; tok < nTok; tok += gridDim.x * 4) {
    const int b = tok / TOK, t = tok % TOK;
    const float4* hrow =
        reinterpret_cast<const float4*>(hs + ((size_t)b * T + t + 1) * HIDDEN);
    float acc[NL];
#pragma unroll
    for (int l = 0; l < NL; ++l) acc[l] = 0.f;
#pragma unroll
    for (int k = 0; k < 4; ++k) {
      const int h4 = lane + 64 * k;
      const float4 hv = hrow[h4];
#pragma unroll
      for (int l = 0; l < NL; ++l) {
        const float4 wv = reinterpret_cast<const float4*>(lw + l * HIDDEN)[h4];
        acc[l] = fmaf(hv.x, wv.x,
                 fmaf(hv.y, wv.y, fmaf(hv.z, wv.z, fmaf(hv.w, wv.w, acc[l]))));
      }
    }
#pragma unroll
    for (int l = 0; l < NL; ++l) {
      float v = acc[l];
#pragma unroll
      for (int off = 32; off; off >>= 1) v += __shfl_xor(v, off);
      acc[l] = v + bb9[l];
    }
    float m1 = -INFINITY, m2 = -INFINITY;
#pragma unroll
    for (int l = 0; l < NL; ++l) {
      const float v = acc[l];
      if (v > m1) { m2 = m1; m1 = v; }
      else if (v > m2) { m2 = v; }
    }
    const bool unc = (m1 - m2 < LEAN_TAU) && (amask[b * T + t + 1] != 0);
    if (unc) acc[0] += LEAN_DELTA;
    if (lane < NL) {
      float outv = acc[0];
#pragma unroll
      for (int l = 1; l < NL; ++l)
        if (lane == l) outv = acc[l];
      e[(size_t)tok * NL + lane] = outv;
    }
  }
}

// ---------------- Kernel 2: per-chunk log-space matrix products ----------------
// 7 chunks per wave; lane = sub*9 + i holds row i of chunk sub's 9x9 product.
// Factored logsumexp: W = exp(trans) in registers -> 9 exp + 9 log + 81 fma/step.
__global__ __launch_bounds__(64) void chunk_k(
    const float* __restrict__ e, const int* __restrict__ labels,
    const float* __restrict__ trans, float* __restrict__ Pout,
    int B, int T, int C) {
  const int TOK = T - 2;
  __shared__ float e2[7][LCH][NL];
  __shared__ float tr2[NL * NL];
  __shared__ int msk[7][LCH];
  const int tid = threadIdx.x;
  const int nG = B * C;
  const int gbase = blockIdx.x * 7;

  for (int idx = tid; idx < NL * NL; idx += 64) tr2[idx] = trans[idx];
  for (int idx = tid; idx < 7 * LCH * NL; idx += 64) {
    const int sub = idx / (LCH * NL), rem = idx % (LCH * NL);
    const int step = rem / NL, j = rem % NL;
    const int g = gbase + sub;
    if (g < nG) {
      const int b = g / C, c = g % C;
      const int t = 1 + c * LCH + step;
      if (t < TOK) e2[sub][step][j] = e[((size_t)b * TOK + t) * NL + j];
    }
  }
  for (int idx = tid; idx < 7 * LCH; idx += 64) {
    const int sub = idx / LCH, step = idx % LCH;
    const int g = gbase + sub;
    if (g < nG) {
      const int b = g / C, c = g % C;
      const int t = 1 + c * LCH + step;
      msk[sub][step] = (t < TOK) ? (labels[(size_t)b * T + 1 + t] != -100) : 0;
    }
  }
  __syncthreads();

  const int sub = tid / NL, i = tid % NL;  // sub==7 only for tid 63 (inactive)
  const int g = gbase + sub;
  const bool act = (sub < 7) && (g < nG);
  int len = 1;
  if (act) { const int c = g % C; len = min(LCH, TOK - (1 + c * LCH)); }

  float W[NL][NL];
#pragma unroll
  for (int k = 0; k < NL; ++k)
#pragma unroll
    for (int j = 0; j < NL; ++j) W[k][j] = __expf(tr2[k * NL + j]);

  float P[NL];
  {
    const int m0 = act ? msk[sub][0] : 0;
#pragma unroll
    for (int j = 0; j < NL; ++j)
      P[j] = m0 ? (tr2[i * NL + j] + e2[sub][0][j])
                : ((i == j) ? 0.f : -1e30f);
  }
  for (int step = 1; step < len; ++step) {
    const int mt = msk[sub][step];
    float mx = P[0];
#pragma unroll
    for (int k = 1; k < NL; ++k) mx = fmaxf(mx, P[k]);
    float E[NL];
#pragma unroll
    for (int k = 0; k < NL; ++k) E[k] = __expf(P[k] - mx);
    float Pn[NL];
#pragma unroll
    for (int j = 0; j < NL; ++j) {
      float s = 0.f;
#pragma unroll
      for (int k = 0; k < NL; ++k) s = fmaf(E[k], W[k][j], s);
      Pn[j] = mx + __logf(s) + e2[sub][step][j];
    }
#pragma unroll
    for (int j = 0; j < NL; ++j) P[j] = mt ? Pn[j] : P[j];
  }
  if (act) {
    float* dst = Pout + (size_t)g * 81 + i * NL;
#pragma unroll
    for (int j = 0; j < NL; ++j) dst[j] = P[j];
  }
}

// ---------------- Kernel 3: per-batch combine (num + den fold) ----------------
__global__ __launch_bounds__(64) void combine_k(
    const float* __restrict__ e, const int* __restrict__ labels,
    const float* __restrict__ start_t, const float* __restrict__ end_t,
    const float* __restrict__ trans, const float* __restrict__ Pmat,
    float* __restrict__ llh, int B, int T, int C) {
  const int TOK = T - 2;
  const int b = blockIdx.x, lane = threadIdx.x;
  const float* eb = e + (size_t)b * TOK * NL;
  const int* lb = labels + (size_t)b * T + 1;

  // ---- numerator: chain-free, data-parallel over t ----
  const int g0r = lb[0];
  const int tg0 = (g0r == -100) ? 0 : g0r;
  float nsum = 0.f;
  int pack = -1;  // (t<<4)|tag of last masked step
  for (int t = 1 + lane; t < TOK; t += 64) {
    const int gr = lb[t], pr = lb[t - 1];
    if (gr != -100) {
      const int cur = gr;
      const int prev = (pr == -100) ? 0 : pr;
      nsum += trans[prev * NL + cur] + eb[t * NL + cur];
      pack = (t << 4) | cur;
    }
  }
#pragma unroll
  for (int off = 32; off; off >>= 1) {
    nsum += __shfl_xor(nsum, off);
    pack = max(pack, __shfl_xor(pack, off));
  }
  const int last = (pack < 0) ? tg0 : (pack & 15);
  const float num = start_t[tg0] + eb[tg0] + nsum + end_t[last];

  // ---- denominator: fold C chunk matrices ----
  float alpha = (lane < NL) ? (start_t[lane] + eb[lane]) : -1e30f;
  for (int c = 0; c < C; ++c) {
    const float* Pc = Pmat + ((size_t)b * C + c) * 81;
    float col[NL];
#pragma unroll
    for (int i = 0; i < NL; ++i)
      col[i] = (lane < NL) ? Pc[i * NL + lane] : -1e30f;
    float s[NL];
    float mx = -1e30f;
#pragma unroll
    for (int i = 0; i < NL; ++i) {
      const float ai = __shfl(alpha, i);
      s[i] = ai + col[i];
      mx = fmaxf(mx, s[i]);
    }
    float sum = 0.f;
#pragma unroll
    for (int i = 0; i < NL; ++i) sum += __expf(s[i] - mx);
    const float nx = mx + __logf(sum);
    alpha = (lane < NL) ? nx : -1e30f;
  }
  const float v = (lane < NL) ? (alpha + end_t[lane]) : -1e30f;
  float mx = v;
#pragma unroll
  for (int off = 32; off; off >>= 1) mx = fmaxf(mx, __shfl_xor(mx, off));
  float sum = (lane < NL) ? __expf(v - mx) : 0.f;
#pragma unroll
  for (int off = 32; off; off >>= 1) sum += __shfl_xor(sum, off);
  const float den = mx + __logf(sum);
  if (lane == 0) llh[b] = num - den;
}

// ---------------- Kernel 4: -mean(llh) ----------------
__global__ __launch_bounds__(64) void reduce_k(const float* __restrict__ llh,
                                               float* __restrict__ out, int B) {
  float v = 0.f;
  for (int i = threadIdx.x; i < B; i += 64) v += llh[i];
#pragma unroll
  for (int off = 32; off; off >>= 1) v += __shfl_xor(v, off);
  if (threadIdx.x == 0) out[0] = -v / (float)B;
}

extern "C" void kernel_launch(void* const* d_in, const int* in_sizes, int n_in,
                              void* d_out, int out_size, void* d_ws,
                              size_t ws_size, hipStream_t stream) {
  const float* hs     = (const float*)d_in[0];
  const float* w      = (const float*)d_in[1];
  const float* bias   = (const float*)d_in[2];
  const float* st     = (const float*)d_in[3];
  const float* et     = (const float*)d_in[4];
  const float* tr     = (const float*)d_in[5];
  const int*   amask  = (const int*)d_in[6];
  const int*   labels = (const int*)d_in[7];

  const int T = 512;
  const int B = in_sizes[6] / T;
  const int TOK = T - 2;
  const int C = (TOK - 1 + LCH - 1) / LCH;  // chunks of the 509 recurrence steps

  float* e    = (float*)d_ws;                 // (B, TOK, 9)
  float* llh  = e + (size_t)B * TOK * NL;     // (B,)
  float* Pmat = llh + B;                      // (B*C, 81)

  const int nTok = B * TOK;
  int grid1 = (nTok + 3) / 4;
  if (grid1 > 2048) grid1 = 2048;
  logits_k<<<grid1, 256, 0, stream>>>(hs, w, bias, amask, e, B, T);
  const int nG = B * C;
  chunk_k<<<(nG + 6) / 7, 64, 0, stream>>>(e, labels, tr, Pmat, B, T, C);
  combine_k<<<B, 64, 0, stream>>>(e, labels, st, et, tr, Pmat, llh, B, T, C);
  reduce_k<<<1, 64, 0, stream>>>(llh, (float*)d_out, B);
}

// Round 9
// 80.332 us; speedup vs baseline: 1.1340x; 1.1049x over previous
//
#include <hip/hip_runtime.h>
#include <math.h>

#define HIDDEN 1024
#define NL 9
#define LEAN_TAU 0.25f
#define LEAN_DELTA 0.35f
#define LCH 16  // CRF scan chunk length
#define TPW 2   // tokens per iteration per wave

// ---------------- Kernel 1: emission logits + lean adjust ----------------
// R9: weights live in per-lane REGISTERS (w4[9][4] float4 = 144 VGPR), matched
// to the exact hv slice each lane loads. Zero LDS use -> the 36 ds_read_b128 +
// 54-shfl/token LDS-pipe bottleneck (~750 cyc/token vs 390 HBM budget,
// diagnosed R8) drops to ~324 cyc (shfl only). Preload amortized over 16
// tokens/wave (grid=510 blocks, ~2 blocks/CU at VGPR~220 -> 8 waves/CU).
__global__ __launch_bounds__(256) void logits_k(
    const float* __restrict__ hs, const float* __restrict__ w,
    const float* __restrict__ bias, const int* __restrict__ amask,
    float* __restrict__ e, int B, int T) {
  const int TOK = T - 2;
  const int nTok = B * TOK;
  const int wave = threadIdx.x >> 6, lane = threadIdx.x & 63;

  // lane d owns h = {4d..4d+3} + 256k, k=0..3 — same slice hv loads below.
  float4 w4[NL][4];
#pragma unroll
  for (int l = 0; l < NL; ++l)
#pragma unroll
    for (int k = 0; k < 4; ++k)
      w4[l][k] =
          reinterpret_cast<const float4*>(w + (size_t)l * HIDDEN)[lane + 64 * k];
  float bb9[NL];
#pragma unroll
  for (int l = 0; l < NL; ++l) bb9[l] = bias[l];

  const int stride = gridDim.x * 4 * TPW;
  for (int base = (blockIdx.x * 4 + wave) * TPW; base < nTok; base += stride) {
    float4 hv[TPW][4];
    int bs[TPW], ts[TPW];
    bool act[TPW];
#pragma unroll
    for (int p = 0; p < TPW; ++p) {
      const int tok = base + p;
      act[p] = tok < nTok;
      const int tokc = act[p] ? tok : base;  // base always valid
      bs[p] = tokc / TOK;
      ts[p] = tokc - bs[p] * TOK;
      const float4* hrow = reinterpret_cast<const float4*>(
          hs + ((size_t)bs[p] * T + ts[p] + 1) * HIDDEN);
#pragma unroll
      for (int k = 0; k < 4; ++k) hv[p][k] = hrow[lane + 64 * k];
    }
#pragma unroll
    for (int p = 0; p < TPW; ++p) {
      float acc[NL];
#pragma unroll
      for (int l = 0; l < NL; ++l) {
        float a = 0.f;
#pragma unroll
        for (int k = 0; k < 4; ++k)
          a = fmaf(hv[p][k].x, w4[l][k].x,
              fmaf(hv[p][k].y, w4[l][k].y,
              fmaf(hv[p][k].z, w4[l][k].z, fmaf(hv[p][k].w, w4[l][k].w, a))));
        acc[l] = a;
      }
#pragma unroll
      for (int l = 0; l < NL; ++l) {
        float v = acc[l];
#pragma unroll
        for (int off = 32; off; off >>= 1) v += __shfl_xor(v, off);
        acc[l] = v + bb9[l];
      }
      float m1 = -INFINITY, m2 = -INFINITY;
#pragma unroll
      for (int l = 0; l < NL; ++l) {
        const float v = acc[l];
        if (v > m1) { m2 = m1; m1 = v; }
        else if (v > m2) { m2 = v; }
      }
      const bool unc = (m1 - m2 < LEAN_TAU) &&
                       (amask[bs[p] * T + ts[p] + 1] != 0);
      if (unc) acc[0] += LEAN_DELTA;
      if (act[p] && lane < NL) {
        float outv = acc[0];
#pragma unroll
        for (int l = 1; l < NL; ++l)
          if (lane == l) outv = acc[l];
        e[(size_t)(base + p) * NL + lane] = outv;
      }
    }
  }
}

// ---------------- Kernel 2: per-chunk log-space matrix products ----------------
// 7 chunks per wave; lane = sub*9 + i holds row i of chunk sub's 9x9 product.
// Factored logsumexp: W = exp(trans) in registers -> 9 exp + 9 log + 81 fma/step.
__global__ __launch_bounds__(64) void chunk_k(
    const float* __restrict__ e, const int* __restrict__ labels,
    const float* __restrict__ trans, float* __restrict__ Pout,
    int B, int T, int C) {
  const int TOK = T - 2;
  __shared__ float e2[7][LCH][NL];
  __shared__ float tr2[NL * NL];
  __shared__ int msk[7][LCH];
  const int tid = threadIdx.x;
  const int nG = B * C;
  const int gbase = blockIdx.x * 7;

  for (int idx = tid; idx < NL * NL; idx += 64) tr2[idx] = trans[idx];
  for (int idx = tid; idx < 7 * LCH * NL; idx += 64) {
    const int sub = idx / (LCH * NL), rem = idx % (LCH * NL);
    const int step = rem / NL, j = rem % NL;
    const int g = gbase + sub;
    if (g < nG) {
      const int b = g / C, c = g % C;
      const int t = 1 + c * LCH + step;
      if (t < TOK) e2[sub][step][j] = e[((size_t)b * TOK + t) * NL + j];
    }
  }
  for (int idx = tid; idx < 7 * LCH; idx += 64) {
    const int sub = idx / LCH, step = idx % LCH;
    const int g = gbase + sub;
    if (g < nG) {
      const int b = g / C, c = g % C;
      const int t = 1 + c * LCH + step;
      msk[sub][step] = (t < TOK) ? (labels[(size_t)b * T + 1 + t] != -100) : 0;
    }
  }
  __syncthreads();

  const int sub = tid / NL, i = tid % NL;  // sub==7 only for tid 63 (inactive)
  const int g = gbase + sub;
  const bool act = (sub < 7) && (g < nG);
  int len = 1;
  if (act) { const int c = g % C; len = min(LCH, TOK - (1 + c * LCH)); }

  float W[NL][NL];
#pragma unroll
  for (int k = 0; k < NL; ++k)
#pragma unroll
    for (int j = 0; j < NL; ++j) W[k][j] = __expf(tr2[k * NL + j]);

  float P[NL];
  {
    const int m0 = act ? msk[sub][0] : 0;
#pragma unroll
    for (int j = 0; j < NL; ++j)
      P[j] = m0 ? (tr2[i * NL + j] + e2[sub][0][j])
                : ((i == j) ? 0.f : -1e30f);
  }
  for (int step = 1; step < len; ++step) {
    const int mt = msk[sub][step];
    float mx = P[0];
#pragma unroll
    for (int k = 1; k < NL; ++k) mx = fmaxf(mx, P[k]);
    float E[NL];
#pragma unroll
    for (int k = 0; k < NL; ++k) E[k] = __expf(P[k] - mx);
    float Pn[NL];
#pragma unroll
    for (int j = 0; j < NL; ++j) {
      float s = 0.f;
#pragma unroll
      for (int k = 0; k < NL; ++k) s = fmaf(E[k], W[k][j], s);
      Pn[j] = mx + __logf(s) + e2[sub][step][j];
    }
#pragma unroll
    for (int j = 0; j < NL; ++j) P[j] = mt ? Pn[j] : P[j];
  }
  if (act) {
    float* dst = Pout + (size_t)g * 81 + i * NL;
#pragma unroll
    for (int j = 0; j < NL; ++j) dst[j] = P[j];
  }
}

// ---------------- Kernel 3: per-batch combine (num + den fold) ----------------
__global__ __launch_bounds__(64) void combine_k(
    const float* __restrict__ e, const int* __restrict__ labels,
    const float* __restrict__ start_t, const float* __restrict__ end_t,
    const float* __restrict__ trans, const float* __restrict__ Pmat,
    float* __restrict__ llh, int B, int T, int C) {
  const int TOK = T - 2;
  const int b = blockIdx.x, lane = threadIdx.x;
  const float* eb = e + (size_t)b * TOK * NL;
  const int* lb = labels + (size_t)b * T + 1;

  // ---- numerator: chain-free, data-parallel over t ----
  const int g0r = lb[0];
  const int tg0 = (g0r == -100) ? 0 : g0r;
  float nsum = 0.f;
  int pack = -1;  // (t<<4)|tag of last masked step
  for (int t = 1 + lane; t < TOK; t += 64) {
    const int gr = lb[t], pr = lb[t - 1];
    if (gr != -100) {
      const int cur = gr;
      const int prev = (pr == -100) ? 0 : pr;
      nsum += trans[prev * NL + cur] + eb[t * NL + cur];
      pack = (t << 4) | cur;
    }
  }
#pragma unroll
  for (int off = 32; off; off >>= 1) {
    nsum += __shfl_xor(nsum, off);
    pack = max(pack, __shfl_xor(pack, off));
  }
  const int last = (pack < 0) ? tg0 : (pack & 15);
  const float num = start_t[tg0] + eb[tg0] + nsum + end_t[last];

  // ---- denominator: fold C chunk matrices ----
  float alpha = (lane < NL) ? (start_t[lane] + eb[lane]) : -1e30f;
  for (int c = 0; c < C; ++c) {
    const float* Pc = Pmat + ((size_t)b * C + c) * 81;
    float col[NL];
#pragma unroll
    for (int i = 0; i < NL; ++i)
      col[i] = (lane < NL) ? Pc[i * NL + lane] : -1e30f;
    float s[NL];
    float mx = -1e30f;
#pragma unroll
    for (int i = 0; i < NL; ++i) {
      const float ai = __shfl(alpha, i);
      s[i] = ai + col[i];
      mx = fmaxf(mx, s[i]);
    }
    float sum = 0.f;
#pragma unroll
    for (int i = 0; i < NL; ++i) sum += __expf(s[i] - mx);
    const float nx = mx + __logf(sum);
    alpha = (lane < NL) ? nx : -1e30f;
  }
  const float v = (lane < NL) ? (alpha + end_t[lane]) : -1e30f;
  float mx = v;
#pragma unroll
  for (int off = 32; off; off >>= 1) mx = fmaxf(mx, __shfl_xor(mx, off));
  float sum = (lane < NL) ? __expf(v - mx) : 0.f;
#pragma unroll
  for (int off = 32; off; off >>= 1) sum += __shfl_xor(sum, off);
  const float den = mx + __logf(sum);
  if (lane == 0) llh[b] = num - den;
}

// ---------------- Kernel 4: -mean(llh) ----------------
__global__ __launch_bounds__(64) void reduce_k(const float* __restrict__ llh,
                                               float* __restrict__ out, int B) {
  float v = 0.f;
  for (int i = threadIdx.x; i < B; i += 64) v += llh[i];
#pragma unroll
  for (int off = 32; off; off >>= 1) v += __shfl_xor(v, off);
  if (threadIdx.x == 0) out[0] = -v / (float)B;
}

extern "C" void kernel_launch(void* const* d_in, const int* in_sizes, int n_in,
                              void* d_out, int out_size, void* d_ws,
                              size_t ws_size, hipStream_t stream) {
  const float* hs     = (const float*)d_in[0];
  const float* w      = (const float*)d_in[1];
  const float* bias   = (const float*)d_in[2];
  const float* st     = (const float*)d_in[3];
  const float* et     = (const float*)d_in[4];
  const float* tr     = (const float*)d_in[5];
  const int*   amask  = (const int*)d_in[6];
  const int*   labels = (const int*)d_in[7];

  const int T = 512;
  const int B = in_sizes[6] / T;
  const int TOK = T - 2;
  const int C = (TOK - 1 + LCH - 1) / LCH;  // chunks of the 509 recurrence steps

  float* e    = (float*)d_ws;                 // (B, TOK, 9)
  float* llh  = e + (size_t)B * TOK * NL;     // (B,)
  float* Pmat = llh + B;                      // (B*C, 81)

  const int nTok = B * TOK;
  // ~2 resident blocks/CU at VGPR~220; 16 tokens/wave amortize the preload.
  int grid1 = 510;
  logits_k<<<grid1, 256, 0, stream>>>(hs, w, bias, amask, e, B, T);
  const int nG = B * C;
  chunk_k<<<(nG + 6) / 7, 64, 0, stream>>>(e, labels, tr, Pmat, B, T, C);
  combine_k<<<B, 64, 0, stream>>>(e, labels, st, et, tr, Pmat, llh, B, T, C);
  reduce_k<<<1, 64, 0, stream>>>(llh, (float*)d_out, B);
}